// Round 1
// baseline (166.141 us; speedup 1.0000x reference)
//
#include <hip/hip_runtime.h>
#include <math.h>

#define NF 2048
#define ROWS (32 * 1024)
#define CHUNK 32   // elements per lane (64 lanes * 32 = 2048)

// ---------------------------------------------------------------------------
// Kernel 1: factorize the tridiagonal matrix once.
//   diag_i = softplus(d_i) + 2 ; sub_i = tanh(l_i) ; sup_i = tanh(u_i)
//   Thomas: b'_0 = diag_0 ; b'_i = diag_i - sub_{i-1}*sup_{i-1}/b'_{i-1}
//   Coefficients for the batched solve:
//     g_i  = -sub_{i-1}/b'_{i-1}   (g_0 = 0)        fwd:  d_i = x_i + g_i d_{i-1}
//     ib_i = 1/b'_i                                 bwd:  y_i = ib_i d_i + c_i y_{i+1}
//     c_i  = -sup_i * ib_i          (c_{n-1} = 0)
//   The b' recurrence is parallelized via a 2x2 matrix scan over the
//   leading-minor three-term recurrence p_i = diag_i p_{i-1} - k_{i-1} p_{i-2},
//   normalized each compose (only ratios matter: b'_i = p_i/p_{i-1}).
//   Outputs written in swizzled layout pos = (i%32)*64 + (i/32) so the solve
//   kernel's LDS reads are conflict-free.
// ---------------------------------------------------------------------------
__global__ __launch_bounds__(256) void precompute_kernel(
    const float* __restrict__ d, const float* __restrict__ l,
    const float* __restrict__ u, float* __restrict__ wsg,
    float* __restrict__ wsc, float* __restrict__ wsib) {
  __shared__ float diag_s[NF], tl_s[NF], tu_s[NF], b_s[NF];
  const int tid = threadIdx.x;

  for (int i = tid; i < NF; i += 256) {
    float dv = d[i];
    float sp = (dv > 20.f) ? dv : log1pf(expf(dv));  // softplus, safe
    diag_s[i] = sp + 2.f;
    tl_s[i] = (i < NF - 1) ? tanhf(l[i]) : 0.f;
    tu_s[i] = (i < NF - 1) ? tanhf(u[i]) : 0.f;
  }
  __syncthreads();

  if (tid < 64) {
    const int lane = tid;
    // local product of 32 matrices [[a,b],[1,0]], normalized each step
    float T00 = 1.f, T01 = 0.f, T10 = 0.f, T11 = 1.f;
#pragma unroll 1
    for (int j = 0; j < CHUNK; ++j) {
      int i = lane * CHUNK + j;
      float a = diag_s[i];
      float b = (i > 0) ? -tl_s[i - 1] * tu_s[i - 1] : 0.f;
      float n00 = a * T00 + b * T10;
      float n01 = a * T01 + b * T11;
      T10 = T00; T11 = T01; T00 = n00; T01 = n01;
      float s = 1.f / (fabsf(T00) + fabsf(T01) + 1e-30f);
      T00 *= s; T01 *= s; T10 *= s; T11 *= s;
    }
    // inclusive scan across lanes (compose: cur * earlier)
    for (int ofs = 1; ofs < 64; ofs <<= 1) {
      float U00 = __shfl_up(T00, ofs, 64);
      float U01 = __shfl_up(T01, ofs, 64);
      float U10 = __shfl_up(T10, ofs, 64);
      float U11 = __shfl_up(T11, ofs, 64);
      if (lane >= ofs) {
        float n00 = T00 * U00 + T01 * U10;
        float n01 = T00 * U01 + T01 * U11;
        float n10 = T10 * U00 + T11 * U10;
        float n11 = T10 * U01 + T11 * U11;
        T00 = n00; T01 = n01; T10 = n10; T11 = n11;
        float s = 1.f / (fabsf(T00) + fabsf(T01) + 1e-30f);
        T00 *= s; T01 *= s; T10 *= s; T11 *= s;
      }
    }
    // exclusive: lane l-1's inclusive matrix applied to v_{-1}=[1,0]
    //   p_{l*32-1} = T00(prev), p_{l*32-2} = T10(prev)  (common scale cancels)
    float p1 = __shfl_up(T00, 1, 64);
    float p2 = __shfl_up(T10, 1, 64);
    float bp = (lane == 0) ? 1.f : p1 / p2;  // b'_{l*32-1}
#pragma unroll 1
    for (int j = 0; j < CHUNK; ++j) {
      int i = lane * CHUNK + j;
      float km1 = (i > 0) ? tl_s[i - 1] * tu_s[i - 1] : 0.f;
      float bv = diag_s[i] - km1 / bp;
      b_s[i] = bv;
      bp = bv;
    }
  }
  __syncthreads();

  for (int i = tid; i < NF; i += 256) {
    float invb = 1.f / b_s[i];
    float g = (i > 0) ? -tl_s[i - 1] / b_s[i - 1] : 0.f;
    float c = (i < NF - 1) ? -tu_s[i] * invb : 0.f;
    int pos = (i & 31) * 64 + (i >> 5);
    wsg[pos] = g;
    wsc[pos] = c;
    wsib[pos] = invb;
  }
}

// ---------------------------------------------------------------------------
// Kernel 2: batched solve. One wave per row; 32 contiguous elems per lane in
// registers; forward/backward first-order recurrences via wave affine scans.
// Coefficients staged in LDS, swizzled [j*64+lane] (2-way bank access = free).
// ---------------------------------------------------------------------------
__global__ __launch_bounds__(256) void solve_kernel(
    const float* __restrict__ x, const float* __restrict__ wsg,
    const float* __restrict__ wsc, const float* __restrict__ wsib,
    float* __restrict__ y) {
  __shared__ float g_s[NF], c_s[NF], ib_s[NF];

  for (int t = threadIdx.x; t < NF / 4; t += blockDim.x) {
    ((float4*)g_s)[t] = ((const float4*)wsg)[t];
    ((float4*)c_s)[t] = ((const float4*)wsc)[t];
    ((float4*)ib_s)[t] = ((const float4*)wsib)[t];
  }
  __syncthreads();

  const int lane = threadIdx.x & 63;
  const int wave = (blockIdx.x * blockDim.x + threadIdx.x) >> 6;
  const int nwaves = (gridDim.x * blockDim.x) >> 6;

  for (int row = wave; row < ROWS; row += nwaves) {
    const float* xr = x + (size_t)row * NF + lane * CHUNK;
    float4 v[8];
#pragma unroll
    for (int t = 0; t < 8; ++t) v[t] = ((const float4*)xr)[t];
    float* dd = (float*)v;  // dd[32]

    // ---- forward: d_i = x_i + g_i * d_{i-1} ----
    float P = 1.f, prev = 0.f;
#pragma unroll
    for (int j = 0; j < CHUNK; ++j) {
      float g = g_s[j * 64 + lane];
      float dj = fmaf(g, prev, dd[j]);
      dd[j] = dj;
      prev = dj;
      P *= g;
    }
    // wave inclusive affine scan: lane map (A,B): out = A*carry_in + B
    float A = P, B = prev;
#pragma unroll
    for (int ofs = 1; ofs < 64; ofs <<= 1) {
      float Au = __shfl_up(A, ofs, 64);
      float Bu = __shfl_up(B, ofs, 64);
      if (lane >= ofs) {
        B = fmaf(A, Bu, B);
        A *= Au;
      }
    }
    float carry = __shfl_up(B, 1, 64);
    if (lane == 0) carry = 0.f;
    // apply carry: d_j += (prod_{k<=j} g_k) * carry
    P = 1.f;
#pragma unroll
    for (int j = 0; j < CHUNK; ++j) {
      float g = g_s[j * 64 + lane];
      P *= g;
      dd[j] = fmaf(P, carry, dd[j]);
    }

    // ---- backward: y_i = ib_i*d_i + c_i*y_{i+1} ----
    float Q = 1.f;
    prev = 0.f;
#pragma unroll
    for (int j = CHUNK - 1; j >= 0; --j) {
      float c = c_s[j * 64 + lane];
      float e = ib_s[j * 64 + lane] * dd[j];
      float yj = fmaf(c, prev, e);
      dd[j] = yj;
      prev = yj;
      Q *= c;
    }
    // reverse wave scan: lane map from right-carry: left_val = A*carry + B
    A = Q;
    B = prev;
#pragma unroll
    for (int ofs = 1; ofs < 64; ofs <<= 1) {
      float Ad = __shfl_down(A, ofs, 64);
      float Bd = __shfl_down(B, ofs, 64);
      if (lane + ofs < 64) {
        B = fmaf(A, Bd, B);
        A *= Ad;
      }
    }
    carry = __shfl_down(B, 1, 64);
    if (lane == 63) carry = 0.f;
    Q = 1.f;
#pragma unroll
    for (int j = CHUNK - 1; j >= 0; --j) {
      float c = c_s[j * 64 + lane];
      Q *= c;
      dd[j] = fmaf(Q, carry, dd[j]);
    }

    float* yr = y + (size_t)row * NF + lane * CHUNK;
#pragma unroll
    for (int t = 0; t < 8; ++t) ((float4*)yr)[t] = v[t];
  }
}

extern "C" void kernel_launch(void* const* d_in, const int* in_sizes, int n_in,
                              void* d_out, int out_size, void* d_ws,
                              size_t ws_size, hipStream_t stream) {
  const float* x = (const float*)d_in[0];
  const float* d = (const float*)d_in[1];
  const float* l = (const float*)d_in[2];
  const float* u = (const float*)d_in[3];
  float* out = (float*)d_out;

  float* wsg = (float*)d_ws;          // 2048 floats, swizzled
  float* wsc = wsg + NF;              // 2048 floats
  float* wsib = wsc + NF;             // 2048 floats

  precompute_kernel<<<1, 256, 0, stream>>>(d, l, u, wsg, wsc, wsib);
  solve_kernel<<<2048, 256, 0, stream>>>(x, wsg, wsc, wsib, out);
}